// Round 1
// baseline (265.116 us; speedup 1.0000x reference)
//
#include <hip/hip_runtime.h>
#include <math.h>

// Problem constants (static shapes per reference)
#define KP 16384
#define DP 2048
#define THRESH 0.5f
#define DECAY 0.99f

// ws float layout:
// [2]  (int) idxMin  = argmin(usages)
// [3]  (int) flag    = 1 evict, 0 ema
// [4]  max_all (max of logits)
// [5]  sumexp_all (ema softmax denom, exp(l - max_all))
// [6]  u
// [7]  zz = ||z||^2
// [8          .. 8+K)    logits
// [8+K        .. 8+2K)   zp (z . p_row)
// [8+2K       .. 8+3K)   pp (||p_row||^2)
// [8+3K       .. 8+4K)   logits2 (ema path only)
// total: (8 + 4*16384)*4 = 262176 bytes

__device__ __forceinline__ float waveReduceSum(float v) {
    #pragma unroll
    for (int m = 32; m >= 1; m >>= 1) v += __shfl_xor(v, m, 64);
    return v;
}

__device__ __forceinline__ unsigned int fkey(float v) {
    // monotone float->uint key (order-preserving for all finite floats)
    unsigned int b = __float_as_uint(v);
    return (b & 0x80000000u) ? ~b : (b | 0x80000000u);
}
__device__ __forceinline__ float fkey_inv(unsigned int key) {
    unsigned int b = (key & 0x80000000u) ? (key ^ 0x80000000u) : ~key;
    return __uint_as_float(b);
}

// ---------------- Kernel 1: argmin(usages) (single block) ----------------
__global__ __launch_bounds__(1024) void k_argmin(const float* __restrict__ usages,
                                                 float* __restrict__ W) {
    __shared__ unsigned long long s[1024];
    int t = threadIdx.x;
    unsigned long long best = ~0ULL;
    #pragma unroll
    for (int i = 0; i < KP / 1024; i++) {
        int j = t + i * 1024;
        unsigned long long p = ((unsigned long long)fkey(usages[j]) << 32) | (unsigned int)j;
        if (p < best) best = p;  // min; equal key -> smaller j wins (first occurrence)
    }
    s[t] = best;
    __syncthreads();
    for (int off = 512; off >= 1; off >>= 1) {
        if (t < off) { if (s[t + off] < s[t]) s[t] = s[t + off]; }
        __syncthreads();
    }
    if (t == 0) ((int*)W)[2] = (int)(s[0] & 0xFFFFFFFFu);
}

// ---- Kernel 2: fused dot-products + speculative evict copy (one wave/row) ----
__global__ __launch_bounds__(256) void k_dots_copy(const float* __restrict__ z,
                                                   const float* __restrict__ P,
                                                   const float* __restrict__ temp,
                                                   float* __restrict__ W,
                                                   float* __restrict__ out) {
    const int wave = threadIdx.x >> 6;
    const int lane = threadIdx.x & 63;
    const int r = blockIdx.x * 4 + wave;
    const int idx = ((const int*)W)[2];

    const float* prow = P + (size_t)r * DP;
    float4 pv[8], zv[8];
    #pragma unroll
    for (int i = 0; i < 8; i++) {
        const int c = i * 256 + lane * 4;
        pv[i] = *(const float4*)(prow + c);
        zv[i] = *(const float4*)(z + c);
    }
    float zp = 0.f, pp = 0.f, zz = 0.f;
    #pragma unroll
    for (int i = 0; i < 8; i++) {
        zp += pv[i].x * zv[i].x + pv[i].y * zv[i].y + pv[i].z * zv[i].z + pv[i].w * zv[i].w;
        pp += pv[i].x * pv[i].x + pv[i].y * pv[i].y + pv[i].z * pv[i].z + pv[i].w * pv[i].w;
        zz += zv[i].x * zv[i].x + zv[i].y * zv[i].y + zv[i].z * zv[i].z + zv[i].w * zv[i].w;
    }

    // Speculative evict-layout copy: in-row r -> out-row (r<idx ? r : r-1), row idx dropped.
    // (If the EMA branch is taken, k_ema rewrites every out row from pristine d_in.)
    if (r != idx) {
        const int ro = (r < idx) ? r : r - 1;
        float* orow = out + 3 + (size_t)ro * DP;  // +3: loss/label/u header => scalar stores
        #pragma unroll
        for (int i = 0; i < 8; i++) {
            const int c = i * 256 + lane * 4;
            orow[c + 0] = pv[i].x;
            orow[c + 1] = pv[i].y;
            orow[c + 2] = pv[i].z;
            orow[c + 3] = pv[i].w;
        }
    }

    zp = waveReduceSum(zp);
    pp = waveReduceSum(pp);
    zz = waveReduceSum(zz);
    if (lane == 0) {
        W[8 + r]          = temp[0] * zp / sqrtf(zz * pp);  // logit
        W[8 + KP + r]     = zp;
        W[8 + 2 * KP + r] = pp;
        if (r == 0) W[7] = zz;
    }
}

// ------- Kernel 3: scalars + reductions + evict epilogue (single block) -------
__global__ __launch_bounds__(1024) void k_scalar(const float* __restrict__ z,
                                                 const float* __restrict__ usages,
                                                 const float* __restrict__ beta,
                                                 const float* __restrict__ gamma,
                                                 const float* __restrict__ temp,
                                                 float* __restrict__ W,
                                                 float* __restrict__ out) {
    __shared__ float sf[1024];
    __shared__ unsigned long long sp[1024];
    const int t = threadIdx.x;
    const int idx = ((const int*)W)[2];

    float lg[KP / 1024];
    float mx_all = -INFINITY;
    unsigned long long bestx = 0;  // packed (key<<32)|~j, argmax excluding idx
    #pragma unroll
    for (int i = 0; i < KP / 1024; i++) {
        const int j = t + i * 1024;
        const float v = W[8 + j];
        lg[i] = v;
        mx_all = fmaxf(mx_all, v);
        if (j != idx) {
            unsigned long long p = ((unsigned long long)fkey(v) << 32) | (unsigned int)(~j);
            if (p > bestx) bestx = p;  // max; equal key -> larger ~j = smaller j wins
        }
    }
    sf[t] = mx_all;
    __syncthreads();
    for (int off = 512; off >= 1; off >>= 1) {
        if (t < off) sf[t] = fmaxf(sf[t], sf[t + off]);
        __syncthreads();
    }
    mx_all = sf[0];
    __syncthreads();

    const float u = 1.f / (1.f + expf(-((-mx_all - beta[0]) / gamma[0])));
    const int flag = (u >= THRESH) ? 1 : 0;  // uniform across block
    if (t == 0) {
        out[2] = u;
        ((int*)W)[3] = flag;
        W[4] = mx_all;
        W[6] = u;
    }

    if (flag) {
        // ---------- evict epilogue ----------
        sp[t] = bestx;
        __syncthreads();
        for (int off = 512; off >= 1; off >>= 1) {
            if (t < off) { if (sp[t + off] > sp[t]) sp[t] = sp[t + off]; }
            __syncthreads();
        }
        const unsigned long long bp = sp[0];
        const float mxe = fkey_inv((unsigned int)(bp >> 32));
        const int amax = (int)(~(unsigned int)(bp & 0xFFFFFFFFu));

        const float tq = temp[0];
        const float M2 = fmaxf(mxe, tq);
        float s = 0.f;
        #pragma unroll
        for (int i = 0; i < KP / 1024; i++) {
            const int j = t + i * 1024;
            if (j != idx) s += expf(lg[i] - M2);
        }
        sf[t] = s;
        __syncthreads();
        for (int off = 512; off >= 1; off >>= 1) {
            if (t < off) sf[t] += sf[t + off];
            __syncthreads();
        }
        if (t == 0) {
            const float total = sf[0] + expf(tq - M2);
            out[0] = logf(total);  // loss = logsumexp(l2) - max(l2)
            const int label = (mxe >= tq) ? (amax < idx ? amax : amax - 1) : (KP - 1);
            out[1] = (float)label;
        }
        // new_usages = [usages[src]; 1.0] * DECAY
        float* ou = out + 3 + (size_t)KP * DP;
        #pragma unroll
        for (int i = 0; i < KP / 1024; i++) {
            const int j = t + i * 1024;
            ou[j] = (j < KP - 1) ? usages[j < idx ? j : j + 1] * DECAY : DECAY;
        }
        // new_protos last row = z
        float* orow = out + 3 + (size_t)(KP - 1) * DP;
        orow[t] = z[t];
        orow[t + 1024] = z[t + 1024];
    } else {
        // ---------- ema prep: softmax denominator ----------
        float s = 0.f;
        #pragma unroll
        for (int i = 0; i < KP / 1024; i++) s += expf(lg[i] - mx_all);
        sf[t] = s;
        __syncthreads();
        for (int off = 512; off >= 1; off >>= 1) {
            if (t < off) sf[t] += sf[t + off];
            __syncthreads();
        }
        if (t == 0) W[5] = sf[0];
    }
}

// --------- Kernel 4: EMA rewrite (early-exits in evict case) ---------
__global__ __launch_bounds__(256) void k_ema(const float* __restrict__ z,
                                             const float* __restrict__ P,
                                             const float* __restrict__ usages,
                                             const float* __restrict__ temp,
                                             float* __restrict__ W,
                                             float* __restrict__ out) {
    if (((const int*)W)[3]) return;  // evict branch taken -> nothing to do
    const int wave = threadIdx.x >> 6;
    const int lane = threadIdx.x & 63;
    const int r = blockIdx.x * 4 + wave;

    const float mx = W[4], se = W[5], u = W[6], zz = W[7];
    const float lg = W[8 + r], zp = W[8 + KP + r], pp = W[8 + 2 * KP + r];
    const float y = expf(lg - mx) / se;
    const float delta = y * (1.f - u);
    const float usg = usages[r];
    const float a = delta / (delta + usg);
    const float b = usg / (usg + delta);

    const float* prow = P + (size_t)r * DP;
    float* orow = out + 3 + (size_t)r * DP;
    #pragma unroll
    for (int i = 0; i < 8; i++) {
        const int c = i * 256 + lane * 4;
        const float4 pv = *(const float4*)(prow + c);
        const float4 zv = *(const float4*)(z + c);
        orow[c + 0] = a * zv.x + b * pv.x;
        orow[c + 1] = a * zv.y + b * pv.y;
        orow[c + 2] = a * zv.z + b * pv.z;
        orow[c + 3] = a * zv.w + b * pv.w;
    }
    if (lane == 0) {
        // logits2 analytically: new_p = a*z + b*p
        const float dzn = a * zz + b * zp;          // z . new_p
        const float n2 = a * a * zz + 2.f * a * b * zp + b * b * pp;  // ||new_p||^2
        W[8 + 3 * KP + r] = temp[0] * dzn / sqrtf(zz * n2);
        out[3 + (size_t)KP * DP + r] = (usg + delta) * DECAY;
    }
}

// --------- Kernel 5: EMA loss/label (early-exits in evict case) ---------
__global__ __launch_bounds__(1024) void k_ema_loss(const float* __restrict__ W,
                                                   float* __restrict__ out) {
    if (((const int*)W)[3]) return;
    __shared__ unsigned long long sp[1024];
    __shared__ float sf[1024];
    const int t = threadIdx.x;

    float l2[KP / 1024];
    unsigned long long best = 0;
    #pragma unroll
    for (int i = 0; i < KP / 1024; i++) {
        const int j = t + i * 1024;
        const float v = W[8 + 3 * KP + j];
        l2[i] = v;
        unsigned long long p = ((unsigned long long)fkey(v) << 32) | (unsigned int)(~j);
        if (p > best) best = p;
    }
    sp[t] = best;
    __syncthreads();
    for (int off = 512; off >= 1; off >>= 1) {
        if (t < off) { if (sp[t + off] > sp[t]) sp[t] = sp[t + off]; }
        __syncthreads();
    }
    const unsigned long long bp = sp[0];
    const float mx = fkey_inv((unsigned int)(bp >> 32));
    const int label = (int)(~(unsigned int)(bp & 0xFFFFFFFFu));

    float s = 0.f;
    #pragma unroll
    for (int i = 0; i < KP / 1024; i++) s += expf(l2[i] - mx);
    __syncthreads();
    sf[t] = s;
    __syncthreads();
    for (int off = 512; off >= 1; off >>= 1) {
        if (t < off) sf[t] += sf[t + off];
        __syncthreads();
    }
    if (t == 0) {
        out[0] = logf(sf[0]);  // l2[label] == mx
        out[1] = (float)label;
    }
}

extern "C" void kernel_launch(void* const* d_in, const int* in_sizes, int n_in,
                              void* d_out, int out_size, void* d_ws, size_t ws_size,
                              hipStream_t stream) {
    const float* z      = (const float*)d_in[0];
    const float* P      = (const float*)d_in[1];
    const float* usages = (const float*)d_in[2];
    const float* beta   = (const float*)d_in[3];
    const float* gamma  = (const float*)d_in[4];
    const float* temp   = (const float*)d_in[5];
    float* out = (float*)d_out;
    float* W   = (float*)d_ws;  // needs (8 + 4*KP)*4 = 262176 bytes

    k_argmin<<<1, 1024, 0, stream>>>(usages, W);
    k_dots_copy<<<KP / 4, 256, 0, stream>>>(z, P, temp, W, out);
    k_scalar<<<1, 1024, 0, stream>>>(z, usages, beta, gamma, temp, W, out);
    k_ema<<<KP / 4, 256, 0, stream>>>(z, P, usages, temp, W, out);
    k_ema_loss<<<1, 1024, 0, stream>>>(W, out);
}

// Round 2
// 263.674 us; speedup vs baseline: 1.0055x; 1.0055x over previous
//
#include <hip/hip_runtime.h>
#include <math.h>

// Problem constants (static shapes per reference)
#define KP 16384
#define DP 2048
#define THRESH 0.5f
#define DECAY 0.99f

// ws float layout:
// [2]  (int) idxMin  = argmin(usages)
// [3]  (int) flag    = 1 evict, 0 ema
// [4]  max_all (max of logits)
// [5]  sumexp_all (ema softmax denom, exp(l - max_all))
// [6]  u
// [7]  zz = ||z||^2
// [8          .. 8+K)    logits
// [8+K        .. 8+2K)   zp (z . p_row)
// [8+2K       .. 8+3K)   pp (||p_row||^2)
// [8+3K       .. 8+4K)   logits2 (ema path only)
// total: (8 + 4*16384)*4 = 262176 bytes

__device__ __forceinline__ float waveReduceSum(float v) {
    #pragma unroll
    for (int m = 32; m >= 1; m >>= 1) v += __shfl_xor(v, m, 64);
    return v;
}

__device__ __forceinline__ unsigned int fkey(float v) {
    // monotone float->uint key (order-preserving for all finite floats)
    unsigned int b = __float_as_uint(v);
    return (b & 0x80000000u) ? ~b : (b | 0x80000000u);
}
__device__ __forceinline__ float fkey_inv(unsigned int key) {
    unsigned int b = (key & 0x80000000u) ? (key ^ 0x80000000u) : ~key;
    return __uint_as_float(b);
}

// ---------------- Kernel 1: argmin(usages) (single block) ----------------
__global__ __launch_bounds__(1024) void k_argmin(const float* __restrict__ usages,
                                                 float* __restrict__ W) {
    __shared__ unsigned long long s[1024];
    int t = threadIdx.x;
    unsigned long long best = ~0ULL;
    #pragma unroll
    for (int i = 0; i < KP / 1024; i++) {
        int j = t + i * 1024;
        unsigned long long p = ((unsigned long long)fkey(usages[j]) << 32) | (unsigned int)j;
        if (p < best) best = p;  // min; equal key -> smaller j wins (first occurrence)
    }
    s[t] = best;
    __syncthreads();
    for (int off = 512; off >= 1; off >>= 1) {
        if (t < off) { if (s[t + off] < s[t]) s[t] = s[t + off]; }
        __syncthreads();
    }
    if (t == 0) ((int*)W)[2] = (int)(s[0] & 0xFFFFFFFFu);
}

// ---- Kernel 2: fused dot-products + speculative evict copy (one wave/row) ----
// Store path: wave stages its row in LDS, re-distributes so every global store
// instruction is 64 consecutive dwords (256 B dense) -- the +3 output offset
// makes float4 stores misaligned, and per-component float4 stores are a
// stride-16B quarter-density scatter (4x L2 line-touches; R1 measured 82us).
__global__ __launch_bounds__(256) void k_dots_copy(const float* __restrict__ z,
                                                   const float* __restrict__ P,
                                                   const float* __restrict__ temp,
                                                   float* __restrict__ W,
                                                   float* __restrict__ out) {
    __shared__ float lds[4 * DP];  // 32 KB: one row per wave
    const int wave = threadIdx.x >> 6;
    const int lane = threadIdx.x & 63;
    const int r = blockIdx.x * 4 + wave;
    const int idx = ((const int*)W)[2];

    const float* prow = P + (size_t)r * DP;
    float* wl = lds + wave * DP;

    float zp = 0.f, pp = 0.f, zz = 0.f;
    #pragma unroll
    for (int i = 0; i < 8; i++) {
        const int c = i * 256 + lane * 4;
        const float4 pv = *(const float4*)(prow + c);
        const float4 zv = *(const float4*)(z + c);
        zp += pv.x * zv.x + pv.y * zv.y + pv.z * zv.z + pv.w * zv.w;
        pp += pv.x * pv.x + pv.y * pv.y + pv.z * pv.z + pv.w * pv.w;
        zz += zv.x * zv.x + zv.y * zv.y + zv.z * zv.z + zv.w * zv.w;
        *(float4*)(wl + c) = pv;  // stage for dense store (wave-private, no barrier)
    }

    // Speculative evict-layout copy: in-row r -> out-row (r<idx ? r : r-1), row idx dropped.
    // (If the EMA branch is taken, k_ema rewrites every out row from pristine d_in.)
    if (r != idx) {
        const int ro = (r < idx) ? r : r - 1;
        float* orow = out + 3 + (size_t)ro * DP;
        #pragma unroll
        for (int j = 0; j < DP / 64; j++) {
            orow[j * 64 + lane] = wl[j * 64 + lane];  // dense 256B per store instr
        }
    }

    zp = waveReduceSum(zp);
    pp = waveReduceSum(pp);
    zz = waveReduceSum(zz);
    if (lane == 0) {
        W[8 + r]          = temp[0] * zp / sqrtf(zz * pp);  // logit
        W[8 + KP + r]     = zp;
        W[8 + 2 * KP + r] = pp;
        if (r == 0) W[7] = zz;
    }
}

// ------- Kernel 3: scalars + reductions + evict epilogue (single block) -------
__global__ __launch_bounds__(1024) void k_scalar(const float* __restrict__ z,
                                                 const float* __restrict__ usages,
                                                 const float* __restrict__ beta,
                                                 const float* __restrict__ gamma,
                                                 const float* __restrict__ temp,
                                                 float* __restrict__ W,
                                                 float* __restrict__ out) {
    __shared__ float sf[1024];
    __shared__ unsigned long long sp[1024];
    const int t = threadIdx.x;
    const int idx = ((const int*)W)[2];

    float lg[KP / 1024];
    float mx_all = -INFINITY;
    unsigned long long bestx = 0;  // packed (key<<32)|~j, argmax excluding idx
    #pragma unroll
    for (int i = 0; i < KP / 1024; i++) {
        const int j = t + i * 1024;
        const float v = W[8 + j];
        lg[i] = v;
        mx_all = fmaxf(mx_all, v);
        if (j != idx) {
            unsigned long long p = ((unsigned long long)fkey(v) << 32) | (unsigned int)(~j);
            if (p > bestx) bestx = p;  // max; equal key -> larger ~j = smaller j wins
        }
    }
    sf[t] = mx_all;
    __syncthreads();
    for (int off = 512; off >= 1; off >>= 1) {
        if (t < off) sf[t] = fmaxf(sf[t], sf[t + off]);
        __syncthreads();
    }
    mx_all = sf[0];
    __syncthreads();

    const float u = 1.f / (1.f + expf(-((-mx_all - beta[0]) / gamma[0])));
    const int flag = (u >= THRESH) ? 1 : 0;  // uniform across block
    if (t == 0) {
        out[2] = u;
        ((int*)W)[3] = flag;
        W[4] = mx_all;
        W[6] = u;
    }

    if (flag) {
        // ---------- evict epilogue ----------
        sp[t] = bestx;
        __syncthreads();
        for (int off = 512; off >= 1; off >>= 1) {
            if (t < off) { if (sp[t + off] > sp[t]) sp[t] = sp[t + off]; }
            __syncthreads();
        }
        const unsigned long long bp = sp[0];
        const float mxe = fkey_inv((unsigned int)(bp >> 32));
        const int amax = (int)(~(unsigned int)(bp & 0xFFFFFFFFu));

        const float tq = temp[0];
        const float M2 = fmaxf(mxe, tq);
        float s = 0.f;
        #pragma unroll
        for (int i = 0; i < KP / 1024; i++) {
            const int j = t + i * 1024;
            if (j != idx) s += expf(lg[i] - M2);
        }
        sf[t] = s;
        __syncthreads();
        for (int off = 512; off >= 1; off >>= 1) {
            if (t < off) sf[t] += sf[t + off];
            __syncthreads();
        }
        if (t == 0) {
            const float total = sf[0] + expf(tq - M2);
            out[0] = logf(total);  // loss = logsumexp(l2) - max(l2); l2[label]==max
            const int label = (mxe >= tq) ? (amax < idx ? amax : amax - 1) : (KP - 1);
            out[1] = (float)label;
        }
        // new_usages = [usages[src]; 1.0] * DECAY
        float* ou = out + 3 + (size_t)KP * DP;
        #pragma unroll
        for (int i = 0; i < KP / 1024; i++) {
            const int j = t + i * 1024;
            ou[j] = (j < KP - 1) ? usages[j < idx ? j : j + 1] * DECAY : DECAY;
        }
        // new_protos last row = z
        float* orow = out + 3 + (size_t)(KP - 1) * DP;
        orow[t] = z[t];
        orow[t + 1024] = z[t + 1024];
    } else {
        // ---------- ema prep: softmax denominator ----------
        float s = 0.f;
        #pragma unroll
        for (int i = 0; i < KP / 1024; i++) s += expf(lg[i] - mx_all);
        sf[t] = s;
        __syncthreads();
        for (int off = 512; off >= 1; off >>= 1) {
            if (t < off) sf[t] += sf[t + off];
            __syncthreads();
        }
        if (t == 0) W[5] = sf[0];
    }
}

// --------- Kernel 4: EMA rewrite (early-exits in evict case) ---------
__global__ __launch_bounds__(256) void k_ema(const float* __restrict__ z,
                                             const float* __restrict__ P,
                                             const float* __restrict__ usages,
                                             const float* __restrict__ temp,
                                             float* __restrict__ W,
                                             float* __restrict__ out) {
    if (((const int*)W)[3]) return;  // evict branch taken -> nothing to do
    __shared__ float lds[4 * DP];
    const int wave = threadIdx.x >> 6;
    const int lane = threadIdx.x & 63;
    const int r = blockIdx.x * 4 + wave;

    const float mx = W[4], se = W[5], u = W[6], zz = W[7];
    const float lg = W[8 + r], zp = W[8 + KP + r], pp = W[8 + 2 * KP + r];
    const float y = expf(lg - mx) / se;
    const float delta = y * (1.f - u);
    const float usg = usages[r];
    const float a = delta / (delta + usg);
    const float b = usg / (usg + delta);

    const float* prow = P + (size_t)r * DP;
    float* wl = lds + wave * DP;
    float* orow = out + 3 + (size_t)r * DP;
    #pragma unroll
    for (int i = 0; i < 8; i++) {
        const int c = i * 256 + lane * 4;
        const float4 pv = *(const float4*)(prow + c);
        const float4 zv = *(const float4*)(z + c);
        float4 ov;
        ov.x = a * zv.x + b * pv.x;
        ov.y = a * zv.y + b * pv.y;
        ov.z = a * zv.z + b * pv.z;
        ov.w = a * zv.w + b * pv.w;
        *(float4*)(wl + c) = ov;
    }
    #pragma unroll
    for (int j = 0; j < DP / 64; j++) {
        orow[j * 64 + lane] = wl[j * 64 + lane];  // dense 256B per store instr
    }
    if (lane == 0) {
        // logits2 analytically: new_p = a*z + b*p
        const float dzn = a * zz + b * zp;          // z . new_p
        const float n2 = a * a * zz + 2.f * a * b * zp + b * b * pp;  // ||new_p||^2
        W[8 + 3 * KP + r] = temp[0] * dzn / sqrtf(zz * n2);
        out[3 + (size_t)KP * DP + r] = (usg + delta) * DECAY;
    }
}

// --------- Kernel 5: EMA loss/label (early-exits in evict case) ---------
__global__ __launch_bounds__(1024) void k_ema_loss(const float* __restrict__ W,
                                                   float* __restrict__ out) {
    if (((const int*)W)[3]) return;
    __shared__ unsigned long long sp[1024];
    __shared__ float sf[1024];
    const int t = threadIdx.x;

    float l2[KP / 1024];
    unsigned long long best = 0;
    #pragma unroll
    for (int i = 0; i < KP / 1024; i++) {
        const int j = t + i * 1024;
        const float v = W[8 + 3 * KP + j];
        l2[i] = v;
        unsigned long long p = ((unsigned long long)fkey(v) << 32) | (unsigned int)(~j);
        if (p > best) best = p;
    }
    sp[t] = best;
    __syncthreads();
    for (int off = 512; off >= 1; off >>= 1) {
        if (t < off) { if (sp[t + off] > sp[t]) sp[t] = sp[t + off]; }
        __syncthreads();
    }
    const unsigned long long bp = sp[0];
    const float mx = fkey_inv((unsigned int)(bp >> 32));
    const int label = (int)(~(unsigned int)(bp & 0xFFFFFFFFu));

    float s = 0.f;
    #pragma unroll
    for (int i = 0; i < KP / 1024; i++) s += expf(l2[i] - mx);
    __syncthreads();
    sf[t] = s;
    __syncthreads();
    for (int off = 512; off >= 1; off >>= 1) {
        if (t < off) sf[t] += sf[t + off];
        __syncthreads();
    }
    if (t == 0) {
        out[0] = logf(sf[0]);  // l2[label] == mx
        out[1] = (float)label;
    }
}

extern "C" void kernel_launch(void* const* d_in, const int* in_sizes, int n_in,
                              void* d_out, int out_size, void* d_ws, size_t ws_size,
                              hipStream_t stream) {
    const float* z      = (const float*)d_in[0];
    const float* P      = (const float*)d_in[1];
    const float* usages = (const float*)d_in[2];
    const float* beta   = (const float*)d_in[3];
    const float* gamma  = (const float*)d_in[4];
    const float* temp   = (const float*)d_in[5];
    float* out = (float*)d_out;
    float* W   = (float*)d_ws;  // needs (8 + 4*KP)*4 = 262176 bytes

    k_argmin<<<1, 1024, 0, stream>>>(usages, W);
    k_dots_copy<<<KP / 4, 256, 0, stream>>>(z, P, temp, W, out);
    k_scalar<<<1, 1024, 0, stream>>>(z, usages, beta, gamma, temp, W, out);
    k_ema<<<KP / 4, 256, 0, stream>>>(z, P, usages, temp, W, out);
    k_ema_loss<<<1, 1024, 0, stream>>>(W, out);
}